// Round 5
// baseline (598.508 us; speedup 1.0000x reference)
//
#include <hip/hip_runtime.h>

// RainbowEvolution T=1024 L=32 D=512 P=512 H=2048.
// Inputs fp32 (runtime-verified: bf16 misread NaN'd in rounds 1-2).
// Outputs fp32 (reference dtype; round 3/4's absmax 5.72 == decorrelated-max
// signature of the harness reading packed-bf16 writes as fp32).
// Factorization: everything linear in base_prompts collapses; [T,L,P] never
// materialized. Scratch lives in d_out's aligned_prompts region (67 MB fp32),
// consumed before the final broadcast overwrites it.

typedef unsigned short u16;
typedef unsigned int u32;

static constexpr int T_ = 1024, L_ = 32, D_ = 512, P_ = 512, H_ = 2048;
static constexpr float SCALE = 0.04419417382415922f; // 1/sqrt(512)
static constexpr float EPS_ = 1e-5f;

// scratch (fp32 offsets into ws = (float*)d_out + OFFO_AP)
static constexpr int OFF_QUERY   = 0;        // [32,512]
static constexpr int OFF_TV      = 16384;    // [512]
static constexpr int OFF_PQ      = 16896;    // [512]
static constexpr int OFF_WKTV    = 17408;    // [512]
static constexpr int OFF_WKPQ    = 17920;    // [512]
static constexpr int OFF_U       = 18432;    // [1024]
static constexpr int OFF_V       = 19456;    // [1024]
static constexpr int OFF_C       = 20480;    // [1024]
static constexpr int OFF_PART    = 21504;    // [32,32,512]
static constexpr int OFF_WBASE   = 545792;   // [32,512]
static constexpr int OFF_WKEY    = 562176;   // [32,512]
static constexpr int OFF_WVAL    = 578560;   // [32,512]
static constexpr int OFF_FA      = 594944;   // [32,32]
static constexpr int OFF_EP      = 595968;   // [32,512]
static constexpr int OFF_XIN     = 612352;   // [32,512]
static constexpr int OFF_EVOLVED = 628736;   // [32,512]
static constexpr int OFF_H1      = 645120;   // [32,2048]
static constexpr int OFF_XOUT    = 710656;   // [32,512]
static constexpr int OFF_FLAG    = 727040;   // [1]
// total 727041 floats = 2.9 MB << 16.77M floats available in AP region

// out layout (fp32 element offsets): aligned, aligned_prompts, task_weights, feature_attn
static constexpr int OFFO_AL = 0;
static constexpr int OFFO_AP = 16384;
static constexpr int OFFO_TW = 16384 + 16777216;   // 16793600
static constexpr int OFFO_FA = OFFO_TW + 1024;     // 16794624

__device__ __forceinline__ float b2f(u16 u) {
    union { u32 i; float f; } x; x.i = ((u32)u) << 16; return x.f;
}
template <bool BF>
__device__ __forceinline__ float LD(const void* p, int i) {
    if (BF) return b2f(((const u16*)p)[i]);
    else    return ((const float*)p)[i];
}
__device__ __forceinline__ bool getbf(const float* ws) { return ws[OFF_FLAG] != 0.0f; }

// Dumb-but-sure block reductions: shared buf[NT], thread-0 serial, broadcast.
template <int NT>
__device__ __forceinline__ float dsum(float v, float* buf, int tid) {
    buf[tid] = v; __syncthreads();
    if (tid == 0) { float s = 0.f; for (int i = 0; i < NT; ++i) s += buf[i]; buf[0] = s; }
    __syncthreads();
    float r = buf[0]; __syncthreads();
    return r;
}
template <int NT>
__device__ __forceinline__ float dmax(float v, float* buf, int tid) {
    buf[tid] = v; __syncthreads();
    if (tid == 0) { float s = buf[0]; for (int i = 1; i < NT; ++i) s = fmaxf(s, buf[i]); buf[0] = s; }
    __syncthreads();
    float r = buf[0]; __syncthreads();
    return r;
}

// K0: input dtype detect (bf16 exponent check on base samples); fp32 expected.
__global__ void k_detect(const void* __restrict__ base, float* __restrict__ ws) {
    __shared__ int cnt;
    if (threadIdx.x == 0) cnt = 0;
    __syncthreads();
    u16 u = ((const u16*)base)[threadIdx.x * 262];
    int e = (u >> 7) & 0xFF;
    if (e >= 100 && e <= 135) atomicAdd(&cnt, 1);
    __syncthreads();
    if (threadIdx.x == 0) ws[OFF_FLAG] = (cnt >= 128) ? 1.0f : 0.0f;
}

// K1: b<32: QUERY[b,p] = np[b]@Wq + bq ; b==32: TV[p] = tanh(te@Wt + bt)
template <bool BF>
__device__ void query_body(const void* np, const void* te, const void* Wq, const void* bq,
                           const void* Wt, const void* bt, float* ws) {
    int p = threadIdx.x, b = blockIdx.x;
    if (b < L_) {
        float acc = LD<BF>(bq, p);
        for (int d = 0; d < D_; ++d) acc = fmaf(LD<BF>(np, b * D_ + d), LD<BF>(Wq, d * P_ + p), acc);
        ws[OFF_QUERY + b * P_ + p] = acc;
    } else {
        float acc = LD<BF>(bt, p);
        for (int d = 0; d < D_; ++d) acc = fmaf(LD<BF>(te, d), LD<BF>(Wt, d * P_ + p), acc);
        ws[OFF_TV + p] = tanhf(acc);
    }
}
__global__ void k_query(const void* np, const void* te, const void* Wq, const void* bq,
                        const void* Wt, const void* bt, float* ws) {
    if (getbf(ws)) query_body<true>(np, te, Wq, bq, Wt, bt, ws);
    else           query_body<false>(np, te, Wq, bq, Wt, bt, ws);
}

// K2: PQ[p] = mean_l QUERY[l,p]
__global__ void k_pq(float* __restrict__ ws) {
    int p = threadIdx.x;
    float s = 0.f;
    for (int l = 0; l < L_; ++l) s += ws[OFF_QUERY + l * P_ + p];
    ws[OFF_PQ + p] = s * (1.0f / L_);
}

// K3: WKTV[d] = Wk[d,:]·TV ; WKPQ[d] = Wk[d,:]·PQ
template <bool BF>
__device__ void wk2_body(const void* Wk, float* ws) {
    int d = threadIdx.x;
    float a = 0.f, b = 0.f;
    for (int p = 0; p < P_; ++p) {
        float w = LD<BF>(Wk, d * P_ + p);
        a = fmaf(w, ws[OFF_TV + p], a);
        b = fmaf(w, ws[OFF_PQ + p], b);
    }
    ws[OFF_WKTV + d] = a;
    ws[OFF_WKPQ + d] = b;
}
__global__ void k_wk2(const void* Wk, float* ws) {
    if (getbf(ws)) wk2_body<true>(Wk, ws);
    else           wk2_body<false>(Wk, ws);
}

// K4: per t: s[d] = sum_l base[t,l,d]; U[t] = (s·WKTV)/L ; V[t] = (s·WKPQ)/L
template <bool BF>
__device__ void bbar_body(const void* base, float* ws) {
    __shared__ float buf[512];
    int t = blockIdx.x, d = threadIdx.x;
    float s = 0.f;
    for (int l = 0; l < L_; ++l) s += LD<BF>(base, t * (L_ * D_) + l * D_ + d);
    float up = dsum<512>(s * ws[OFF_WKTV + d], buf, d);
    float vp = dsum<512>(s * ws[OFF_WKPQ + d], buf, d);
    if (d == 0) {
        ws[OFF_U + t] = up * (1.0f / L_);
        ws[OFF_V + t] = vp * (1.0f / L_);
    }
}
__global__ void k_bbar(const void* base, float* ws) {
    if (getbf(ws)) bbar_body<true>(base, ws);
    else           bbar_body<false>(base, ws);
}

// K5: softmax chain -> task_weights out (fp32) and C[t] = tw_t*(1+tw1_t)
template <bool BF>
__device__ void soft_body(const void* bk, float* out_tw, float* ws) {
    __shared__ float buf[256];
    int tid = threadIdx.x;
    float pbt = 0.f, pbq = 0.f;
    for (int p = tid; p < P_; p += 256) {
        float bkf = LD<BF>(bk, p);
        pbt = fmaf(bkf, ws[OFF_TV + p], pbt);
        pbq = fmaf(bkf, ws[OFF_PQ + p], pbq);
    }
    float bkt = dsum<256>(pbt, buf, tid);
    float bkq = dsum<256>(pbq, buf, tid);

    float s1[4], e1[4], tw1[4], lmax = -1e30f;
    #pragma unroll
    for (int k = 0; k < 4; ++k) {
        s1[k] = (ws[OFF_U + tid + k * 256] + bkt) * SCALE;
        lmax = fmaxf(lmax, s1[k]);
    }
    float gmax = dmax<256>(lmax, buf, tid);
    float ls = 0.f;
    #pragma unroll
    for (int k = 0; k < 4; ++k) { e1[k] = expf(s1[k] - gmax); ls += e1[k]; }
    float gs = dsum<256>(ls, buf, tid);
    #pragma unroll
    for (int k = 0; k < 4; ++k) tw1[k] = e1[k] / gs;

    float p2[4], e2[4];
    lmax = -1e30f;
    #pragma unroll
    for (int k = 0; k < 4; ++k) {
        p2[k] = ((1.0f + tw1[k]) * ws[OFF_V + tid + k * 256] + bkq) * SCALE;
        lmax = fmaxf(lmax, p2[k]);
    }
    gmax = dmax<256>(lmax, buf, tid);
    ls = 0.f;
    #pragma unroll
    for (int k = 0; k < 4; ++k) { e2[k] = expf(p2[k] - gmax); ls += e2[k]; }
    gs = dsum<256>(ls, buf, tid);

    float tw[4], lsum = 0.f;
    #pragma unroll
    for (int k = 0; k < 4; ++k) { tw[k] = 0.5f * tw1[k] + 0.5f * (e2[k] / gs); lsum += tw[k]; }
    float S = dsum<256>(lsum, buf, tid);
    S = fmaxf(S, 1e-6f);
    #pragma unroll
    for (int k = 0; k < 4; ++k) {
        int t = tid + k * 256;
        float twn = tw[k] / S;
        out_tw[t] = twn;
        ws[OFF_C + t] = twn * (1.0f + tw1[k]);
    }
}
__global__ void k_soft(const void* bk, float* out_tw, float* ws) {
    if (getbf(ws)) soft_body<true>(bk, out_tw, ws);
    else           soft_body<false>(bk, out_tw, ws);
}

// K6: PART[ch,l,d] = sum_{i<32} C[ch*32+i] * base[ch*32+i, l, d]
template <bool BF>
__device__ void wpart_body(const void* base, float* ws) {
    __shared__ float cs[32];
    int l = blockIdx.x, ch = blockIdx.y, d = threadIdx.x;
    if (d < 32) cs[d] = ws[OFF_C + ch * 32 + d];
    __syncthreads();
    float acc = 0.f;
    for (int i = 0; i < 32; ++i) {
        int t = ch * 32 + i;
        acc = fmaf(cs[i], LD<BF>(base, (t * L_ + l) * D_ + d), acc);
    }
    ws[OFF_PART + (ch * L_ + l) * D_ + d] = acc;
}
__global__ void k_wpart(const void* base, float* ws) {
    if (getbf(ws)) wpart_body<true>(base, ws);
    else           wpart_body<false>(base, ws);
}

// K7: WBASE[l,d] = sum_ch PART[ch,l,d]
__global__ void k_wred(float* __restrict__ ws) {
    int l = blockIdx.x, d = threadIdx.x;
    float s = 0.f;
    for (int ch = 0; ch < 32; ++ch) s += ws[OFF_PART + (ch * L_ + l) * D_ + d];
    ws[OFF_WBASE + l * D_ + d] = s;
}

// K8: WKEY[l,p] = WBASE[l,:]@Wk + bk ; WVAL likewise with Wv (sel=blockIdx.y)
template <bool BF>
__device__ void wkv_body(const void* Wk, const void* bk, const void* Wv, const void* bv,
                         float* ws) {
    int l = blockIdx.x, sel = blockIdx.y, p = threadIdx.x;
    const void* W = sel ? Wv : Wk;
    const void* bb = sel ? bv : bk;
    float acc = LD<BF>(bb, p);
    for (int d = 0; d < D_; ++d) acc = fmaf(ws[OFF_WBASE + l * D_ + d], LD<BF>(W, d * P_ + p), acc);
    ws[(sel ? OFF_WVAL : OFF_WKEY) + l * P_ + p] = acc;
}
__global__ void k_wkv(const void* Wk, const void* bk, const void* Wv, const void* bv, float* ws) {
    if (getbf(ws)) wkv_body<true>(Wk, bk, Wv, bv, ws);
    else           wkv_body<false>(Wk, bk, Wv, bv, ws);
}

// K9: feature logits + row softmax. 1 block, 1024 threads (l = tid>>5, g = tid&31).
__global__ void k_logits(float* __restrict__ out_fa, float* __restrict__ ws) {
    __shared__ float lg[1024];
    int tid = threadIdx.x, l = tid >> 5, g = tid & 31;
    float a = 0.f;
    for (int p = 0; p < P_; ++p)
        a = fmaf(ws[OFF_QUERY + l * P_ + p], ws[OFF_WKEY + g * P_ + p], a);
    lg[tid] = a * SCALE;
    __syncthreads();
    float mx = -1e30f;
    for (int i = 0; i < 32; ++i) mx = fmaxf(mx, lg[l * 32 + i]);
    float s = 0.f;
    for (int i = 0; i < 32; ++i) s += expf(lg[l * 32 + i] - mx);
    float f = expf(lg[tid] - mx) / s;
    ws[OFF_FA + tid] = f;
    out_fa[tid] = f;
}

// K10: EP[l,p] = sum_j FA[l,j]*WVAL[j,p]
__global__ void k_ep(float* __restrict__ ws) {
    int l = blockIdx.x, p = threadIdx.x;
    float acc = 0.f;
    for (int j = 0; j < L_; ++j)
        acc = fmaf(ws[OFF_FA + l * 32 + j], ws[OFF_WVAL + j * P_ + p], acc);
    ws[OFF_EP + l * P_ + p] = acc;
}

// K11: XIN[l,d] = WBASE[l,d] + EP[l,:]@Wo + bo
template <bool BF>
__device__ void evo_body(const void* Wo, const void* bo, float* ws) {
    int l = blockIdx.x, d = threadIdx.x;
    float acc = LD<BF>(bo, d);
    for (int p = 0; p < P_; ++p) acc = fmaf(ws[OFF_EP + l * P_ + p], LD<BF>(Wo, p * D_ + d), acc);
    ws[OFF_XIN + l * D_ + d] = ws[OFF_WBASE + l * D_ + d] + acc;
}
__global__ void k_evo(const void* Wo, const void* bo, float* ws) {
    if (getbf(ws)) evo_body<true>(Wo, bo, ws);
    else           evo_body<false>(Wo, bo, ws);
}

// K12: EVOLVED = LN(XIN)*g_in + b_in
template <bool BF>
__device__ void lnin_body(const void* g_in, const void* b_in, float* ws) {
    __shared__ float buf[512];
    int l = blockIdx.x, d = threadIdx.x;
    float x = ws[OFF_XIN + l * D_ + d];
    float mean = dsum<512>(x, buf, d) * (1.0f / D_);
    float dx = x - mean;
    float var = dsum<512>(dx * dx, buf, d) * (1.0f / D_);
    ws[OFF_EVOLVED + l * D_ + d] = dx * rsqrtf(var + EPS_) * LD<BF>(g_in, d) + LD<BF>(b_in, d);
}
__global__ void k_lnin(const void* g_in, const void* b_in, float* ws) {
    if (getbf(ws)) lnin_body<true>(g_in, b_in, ws);
    else           lnin_body<false>(g_in, b_in, ws);
}

// K13: H1[l,h] = relu(EVOLVED[l,:]@Wa1 + ba1); grid (32 l, 4 h-chunks) x 512
template <bool BF>
__device__ void mlp1_body(const void* Wa1, const void* ba1, float* ws) {
    int l = blockIdx.x, h = blockIdx.y * 512 + threadIdx.x;
    float acc = LD<BF>(ba1, h);
    for (int d = 0; d < D_; ++d) acc = fmaf(ws[OFF_EVOLVED + l * D_ + d], LD<BF>(Wa1, d * H_ + h), acc);
    ws[OFF_H1 + l * H_ + h] = fmaxf(acc, 0.f);
}
__global__ void k_mlp1(const void* Wa1, const void* ba1, float* ws) {
    if (getbf(ws)) mlp1_body<true>(Wa1, ba1, ws);
    else           mlp1_body<false>(Wa1, ba1, ws);
}

// K14: XOUT[l,d] = EVOLVED[l,d] + H1[l,:]@Wa2 + ba2
template <bool BF>
__device__ void mlp2_body(const void* Wa2, const void* ba2, float* ws) {
    int l = blockIdx.x, d = threadIdx.x;
    float acc = LD<BF>(ba2, d);
    for (int h = 0; h < H_; ++h) acc = fmaf(ws[OFF_H1 + l * H_ + h], LD<BF>(Wa2, h * D_ + d), acc);
    ws[OFF_XOUT + l * D_ + d] = ws[OFF_EVOLVED + l * D_ + d] + acc;
}
__global__ void k_mlp2(const void* Wa2, const void* ba2, float* ws) {
    if (getbf(ws)) mlp2_body<true>(Wa2, ba2, ws);
    else           mlp2_body<false>(Wa2, ba2, ws);
}

// K15: aligned = LN(XOUT)*g_out + b_out -> fp32 out
template <bool BF>
__device__ void lnout_body(const void* g_out, const void* b_out, float* out_al, float* ws) {
    __shared__ float buf[512];
    int l = blockIdx.x, d = threadIdx.x;
    float x = ws[OFF_XOUT + l * D_ + d];
    float mean = dsum<512>(x, buf, d) * (1.0f / D_);
    float dx = x - mean;
    float var = dsum<512>(dx * dx, buf, d) * (1.0f / D_);
    out_al[l * D_ + d] = dx * rsqrtf(var + EPS_) * LD<BF>(g_out, d) + LD<BF>(b_out, d);
}
__global__ void k_lnout(const void* g_out, const void* b_out, float* out_al, float* ws) {
    if (getbf(ws)) lnout_body<true>(g_out, b_out, out_al, ws);
    else           lnout_body<false>(g_out, b_out, out_al, ws);
}

// K16: aligned_prompts = broadcast(aligned), fp32, 64 MB write via float4.
// Runs LAST; overwrites the AP-region scratch.
__global__ void k_bcast(float* __restrict__ out) {
    const float4* src = (const float4*)out;       // 4096 float4 = 16384 floats
    float4* dst = (float4*)(out + OFFO_AP);
    int idx = blockIdx.x * 256 + threadIdx.x;     // 4096 blocks -> 1048576
    #pragma unroll
    for (int k = 0; k < 4; ++k) {
        int v = idx + k * 1048576;                // total 4194304 float4
        dst[v] = src[v & 4095];
    }
}

extern "C" void kernel_launch(void* const* d_in, const int* in_sizes, int n_in,
                              void* d_out, int out_size, void* d_ws, size_t ws_size,
                              hipStream_t stream) {
    const void* base = d_in[0];
    const void* np   = d_in[1];
    const void* te   = d_in[2];
    const void* Wt   = d_in[3];
    const void* bt   = d_in[4];
    const void* Wq   = d_in[5];
    const void* bq   = d_in[6];
    const void* Wk   = d_in[7];
    const void* bk   = d_in[8];
    const void* Wv   = d_in[9];
    const void* bv   = d_in[10];
    const void* Wo   = d_in[11];
    const void* bo   = d_in[12];
    const void* Wa1  = d_in[13];
    const void* ba1  = d_in[14];
    const void* Wa2  = d_in[15];
    const void* ba2  = d_in[16];
    const void* g_in = d_in[17];
    const void* b_in = d_in[18];
    const void* g_out= d_in[19];
    const void* b_out= d_in[20];
    float* out = (float*)d_out;
    float* ws = out + OFFO_AP;   // scratch inside fp32 AP output region

    hipLaunchKernelGGL(k_detect, dim3(1),      dim3(256), 0, stream, base, ws);
    hipLaunchKernelGGL(k_query,  dim3(33),     dim3(512), 0, stream, np, te, Wq, bq, Wt, bt, ws);
    hipLaunchKernelGGL(k_pq,     dim3(1),      dim3(512), 0, stream, ws);
    hipLaunchKernelGGL(k_wk2,    dim3(1),      dim3(512), 0, stream, Wk, ws);
    hipLaunchKernelGGL(k_bbar,   dim3(1024),   dim3(512), 0, stream, base, ws);
    hipLaunchKernelGGL(k_soft,   dim3(1),      dim3(256), 0, stream, bk, out + OFFO_TW, ws);
    hipLaunchKernelGGL(k_wpart,  dim3(32, 32), dim3(512), 0, stream, base, ws);
    hipLaunchKernelGGL(k_wred,   dim3(32),     dim3(512), 0, stream, ws);
    hipLaunchKernelGGL(k_wkv,    dim3(32, 2),  dim3(512), 0, stream, Wk, bk, Wv, bv, ws);
    hipLaunchKernelGGL(k_logits, dim3(1),      dim3(1024), 0, stream, out + OFFO_FA, ws);
    hipLaunchKernelGGL(k_ep,     dim3(32),     dim3(512), 0, stream, ws);
    hipLaunchKernelGGL(k_evo,    dim3(32),     dim3(512), 0, stream, Wo, bo, ws);
    hipLaunchKernelGGL(k_lnin,   dim3(32),     dim3(512), 0, stream, g_in, b_in, ws);
    hipLaunchKernelGGL(k_mlp1,   dim3(32, 4),  dim3(512), 0, stream, Wa1, ba1, ws);
    hipLaunchKernelGGL(k_mlp2,   dim3(32),     dim3(512), 0, stream, Wa2, ba2, ws);
    hipLaunchKernelGGL(k_lnout,  dim3(32),     dim3(512), 0, stream, g_out, b_out, out + OFFO_AL, ws);
    hipLaunchKernelGGL(k_bcast,  dim3(4096),   dim3(256), 0, stream, out);
}

// Round 6
// 254.641 us; speedup vs baseline: 2.3504x; 2.3504x over previous
//
#include <hip/hip_runtime.h>

// RainbowEvolution T=1024 L=32 D=512 P=512 H=2048. fp32 in / fp32 out (verified R5).
// Linear-in-base factorization; [T,L,P] never materialized.
// R6: split-K GEMMs w/ LDS-staged activations + atomicAdd accumulators (k_zero'd),
// wave-level shuffle reductions, float4 base scans. Scratch in d_out's
// aligned_prompts region (67 MB), consumed before k_bcast overwrites it.

typedef unsigned int u32;

static constexpr int T_ = 1024, L_ = 32, D_ = 512, P_ = 512, H_ = 2048;
static constexpr float SCALE = 0.04419417382415922f; // 1/sqrt(512)
static constexpr float EPS_ = 1e-5f;

// scratch (fp32 offsets into ws = (float*)d_out + OFFO_AP)
static constexpr int OFF_QUERY   = 0;        // [32,512]
static constexpr int OFF_TV      = 16384;    // [512]
static constexpr int OFF_PQ      = 16896;    // [512]
static constexpr int OFF_WKTV    = 17408;    // [512]
static constexpr int OFF_WKPQ    = 17920;    // [512]
static constexpr int OFF_U       = 18432;    // [1024]
static constexpr int OFF_V       = 19456;    // [1024]
static constexpr int OFF_C       = 20480;    // [1024]
static constexpr int OFF_PART    = 21504;    // [32ch,32l,512]
static constexpr int OFF_WBASE   = 545792;   // [32,512]
static constexpr int OFF_WKEY    = 562176;   // [32,512]
static constexpr int OFF_WVAL    = 578560;   // [32,512]
static constexpr int OFF_FA      = 594944;   // [32,32]
static constexpr int OFF_EP      = 595968;   // [32,512]
static constexpr int OFF_EVOLVED = 612352;   // [32,512]
// zeroed accumulator region (contiguous):
static constexpr int OFF_AQ      = 628736;   // [33,512] query/tv pre-bias
static constexpr int OFF_AKV     = 645632;   // [2,32,512]
static constexpr int OFF_AEVO    = 678400;   // [32,512]
static constexpr int OFF_AH1     = 694784;   // [32,2048] pre-bias pre-relu
static constexpr int OFF_AOUT    = 760320;   // [32,512]
static constexpr int ZERO_BEGIN  = OFF_AQ;
static constexpr int ZERO_F4     = (776704 - 628736) / 4;   // 36992 float4

// out layout (fp32 offsets): aligned, aligned_prompts, task_weights, feature_attn
static constexpr int OFFO_AL = 0;
static constexpr int OFFO_AP = 16384;
static constexpr int OFFO_TW = 16384 + 16777216;   // 16793600
static constexpr int OFFO_FA = OFFO_TW + 1024;     // 16794624

// ---- reductions ----
__device__ __forceinline__ float wred(float v) {
    #pragma unroll
    for (int off = 32; off > 0; off >>= 1) v += __shfl_down(v, off, 64);
    return v;  // valid in lane 0
}
template <int NT>
__device__ __forceinline__ float fsum(float v, float* buf, int tid) {
    v = wred(v);
    if ((tid & 63) == 0) buf[tid >> 6] = v;
    __syncthreads();
    if (tid == 0) { float s = 0.f; for (int i = 0; i < NT / 64; ++i) s += buf[i]; buf[0] = s; }
    __syncthreads();
    float r = buf[0]; __syncthreads();
    return r;
}
template <int NT>
__device__ __forceinline__ float fmaxr(float v, float* buf, int tid) {
    #pragma unroll
    for (int off = 32; off > 0; off >>= 1) v = fmaxf(v, __shfl_down(v, off, 64));
    if ((tid & 63) == 0) buf[tid >> 6] = v;
    __syncthreads();
    if (tid == 0) { float s = buf[0]; for (int i = 1; i < NT / 64; ++i) s = fmaxf(s, buf[i]); buf[0] = s; }
    __syncthreads();
    float r = buf[0]; __syncthreads();
    return r;
}

// K-zero: zero the atomic accumulator region
__global__ void k_zero(float* __restrict__ ws) {
    int i = blockIdx.x * 256 + threadIdx.x;
    if (i < ZERO_F4) ((float4*)(ws + ZERO_BEGIN))[i] = make_float4(0.f, 0.f, 0.f, 0.f);
}

// K1: split-K (np|te) @ (Wq|Wt) -> AQ. grid(33, 4kc), block 512.
__global__ void k_query_g(const float* __restrict__ np, const float* __restrict__ te,
                          const float* __restrict__ Wq, const float* __restrict__ Wt,
                          float* __restrict__ ws) {
    __shared__ float sx[128];
    int p = threadIdx.x, b = blockIdx.x, kc = blockIdx.y;
    const float* x = (b < L_) ? (np + b * D_) : te;
    if (p < 128) sx[p] = x[kc * 128 + p];
    __syncthreads();
    const float* W = (b < L_) ? Wq : Wt;
    float acc = 0.f;
    #pragma unroll 8
    for (int j = 0; j < 128; ++j) acc = fmaf(sx[j], W[(kc * 128 + j) * P_ + p], acc);
    atomicAdd(&ws[OFF_AQ + b * P_ + p], acc);
}

// K2: epilogue: QUERY = AQ + bq ; TV = tanh(AQ[32] + bt)
__global__ void k_query_ep(const float* __restrict__ bq, const float* __restrict__ bt,
                           float* __restrict__ ws) {
    int p = threadIdx.x, b = blockIdx.x;
    if (b < L_) ws[OFF_QUERY + b * P_ + p] = ws[OFF_AQ + b * P_ + p] + bq[p];
    else        ws[OFF_TV + p] = tanhf(ws[OFF_AQ + L_ * P_ + p] + bt[p]);
}

// K3: PQ[p] = mean_l QUERY[l,p]
__global__ void k_pq(float* __restrict__ ws) {
    int p = threadIdx.x;
    float s = 0.f;
    for (int l = 0; l < L_; ++l) s += ws[OFF_QUERY + l * P_ + p];
    ws[OFF_PQ + p] = s * (1.0f / L_);
}

// K4: WKTV[d]=Wk[d,:]·TV, WKPQ[d]=Wk[d,:]·PQ. wave-per-d, float4, grid 64 x 512.
__global__ void k_wk2(const float* __restrict__ Wk, float* __restrict__ ws) {
    int tid = threadIdx.x, wv = tid >> 6, lane = tid & 63;
    int d = blockIdx.x * 8 + wv;
    const float4* row = (const float4*)(Wk + d * P_);
    const float4* tv4 = (const float4*)(ws + OFF_TV);
    const float4* pq4 = (const float4*)(ws + OFF_PQ);
    float4 a = row[lane * 2], b = row[lane * 2 + 1];
    float4 t0 = tv4[lane * 2], t1 = tv4[lane * 2 + 1];
    float4 q0 = pq4[lane * 2], q1 = pq4[lane * 2 + 1];
    float pa = a.x * t0.x + a.y * t0.y + a.z * t0.z + a.w * t0.w
             + b.x * t1.x + b.y * t1.y + b.z * t1.z + b.w * t1.w;
    float pb = a.x * q0.x + a.y * q0.y + a.z * q0.z + a.w * q0.w
             + b.x * q1.x + b.y * q1.y + b.z * q1.z + b.w * q1.w;
    pa = wred(pa); pb = wred(pb);
    if (lane == 0) { ws[OFF_WKTV + d] = pa; ws[OFF_WKPQ + d] = pb; }
}

// K5: per t: s[d]=sum_l base[t,l,d]; U[t]=(s·WKTV)/L ; V[t]=(s·WKPQ)/L
__global__ void k_bbar(const float* __restrict__ base, float* __restrict__ ws) {
    __shared__ float buf[8];
    int t = blockIdx.x, d = threadIdx.x;
    const float* bp = base + (size_t)t * (L_ * D_);
    float s = 0.f;
    for (int l = 0; l < L_; ++l) s += bp[l * D_ + d];
    float up = fsum<512>(s * ws[OFF_WKTV + d], buf, d);
    float vp = fsum<512>(s * ws[OFF_WKPQ + d], buf, d);
    if (d == 0) {
        ws[OFF_U + t] = up * (1.0f / L_);
        ws[OFF_V + t] = vp * (1.0f / L_);
    }
}

// K6: softmax chain -> task_weights (fp32 out) and C[t]=tw_t*(1+tw1_t)
__global__ void k_soft(const float* __restrict__ bk, float* __restrict__ out_tw,
                       float* __restrict__ ws) {
    __shared__ float buf[8];
    int tid = threadIdx.x;
    float pbt = 0.f, pbq = 0.f;
    for (int p = tid; p < P_; p += 256) {
        float bkf = bk[p];
        pbt = fmaf(bkf, ws[OFF_TV + p], pbt);
        pbq = fmaf(bkf, ws[OFF_PQ + p], pbq);
    }
    float bkt = fsum<256>(pbt, buf, tid);
    float bkq = fsum<256>(pbq, buf, tid);

    float s1[4], e1[4], tw1[4], lmax = -1e30f;
    #pragma unroll
    for (int k = 0; k < 4; ++k) {
        s1[k] = (ws[OFF_U + tid + k * 256] + bkt) * SCALE;
        lmax = fmaxf(lmax, s1[k]);
    }
    float gmax = fmaxr<256>(lmax, buf, tid);
    float ls = 0.f;
    #pragma unroll
    for (int k = 0; k < 4; ++k) { e1[k] = expf(s1[k] - gmax); ls += e1[k]; }
    float gs = fsum<256>(ls, buf, tid);
    #pragma unroll
    for (int k = 0; k < 4; ++k) tw1[k] = e1[k] / gs;

    float p2[4], e2[4];
    lmax = -1e30f;
    #pragma unroll
    for (int k = 0; k < 4; ++k) {
        p2[k] = ((1.0f + tw1[k]) * ws[OFF_V + tid + k * 256] + bkq) * SCALE;
        lmax = fmaxf(lmax, p2[k]);
    }
    gmax = fmaxr<256>(lmax, buf, tid);
    ls = 0.f;
    #pragma unroll
    for (int k = 0; k < 4; ++k) { e2[k] = expf(p2[k] - gmax); ls += e2[k]; }
    gs = fsum<256>(ls, buf, tid);

    float tw[4], lsum = 0.f;
    #pragma unroll
    for (int k = 0; k < 4; ++k) { tw[k] = 0.5f * tw1[k] + 0.5f * (e2[k] / gs); lsum += tw[k]; }
    float S = fsum<256>(lsum, buf, tid);
    S = fmaxf(S, 1e-6f);
    #pragma unroll
    for (int k = 0; k < 4; ++k) {
        int t = tid + k * 256;
        float twn = tw[k] / S;
        out_tw[t] = twn;
        ws[OFF_C + t] = twn * (1.0f + tw1[k]);
    }
}

// K7: PART[ch,l,:] = sum_{i<32} C[ch*32+i]*base[ch*32+i,l,:], float4. grid(32l,32ch) x128.
__global__ void k_wpart(const float* __restrict__ base, float* __restrict__ ws) {
    __shared__ float cs[32];
    int l = blockIdx.x, ch = blockIdx.y, tid = threadIdx.x;
    if (tid < 32) cs[tid] = ws[OFF_C + ch * 32 + tid];
    __syncthreads();
    float a0 = 0.f, a1 = 0.f, a2 = 0.f, a3 = 0.f;
    for (int i = 0; i < 32; ++i) {
        int t = ch * 32 + i;
        float4 v = ((const float4*)(base + ((size_t)t * L_ + l) * D_))[tid];
        float cc = cs[i];
        a0 = fmaf(cc, v.x, a0); a1 = fmaf(cc, v.y, a1);
        a2 = fmaf(cc, v.z, a2); a3 = fmaf(cc, v.w, a3);
    }
    ((float4*)(ws + OFF_PART + (ch * L_ + l) * D_))[tid] = make_float4(a0, a1, a2, a3);
}

// K8: WBASE[l,d] = sum_ch PART[ch,l,d]
__global__ void k_wred(float* __restrict__ ws) {
    int l = blockIdx.x, d = threadIdx.x;
    float s = 0.f;
    for (int ch = 0; ch < 32; ++ch) s += ws[OFF_PART + (ch * L_ + l) * D_ + d];
    ws[OFF_WBASE + l * D_ + d] = s;
}

// K9: split-K WBASE @ (Wk|Wv) -> AKV. grid(32l, 2sel, 4kc), block 512.
__global__ void k_wkv_g(const float* __restrict__ Wk, const float* __restrict__ Wv,
                        float* __restrict__ ws) {
    __shared__ float sx[128];
    int p = threadIdx.x, l = blockIdx.x, sel = blockIdx.y, kc = blockIdx.z;
    if (p < 128) sx[p] = ws[OFF_WBASE + l * D_ + kc * 128 + p];
    __syncthreads();
    const float* W = sel ? Wv : Wk;
    float acc = 0.f;
    #pragma unroll 8
    for (int j = 0; j < 128; ++j) acc = fmaf(sx[j], W[(kc * 128 + j) * P_ + p], acc);
    atomicAdd(&ws[OFF_AKV + (sel * L_ + l) * P_ + p], acc);
}

// K10: WKEY/WVAL = AKV + bias
__global__ void k_wkv_ep(const float* __restrict__ bk, const float* __restrict__ bv,
                         float* __restrict__ ws) {
    int p = threadIdx.x, l = blockIdx.x, sel = blockIdx.y;
    float b = sel ? bv[p] : bk[p];
    ws[(sel ? OFF_WVAL : OFF_WKEY) + l * P_ + p] = ws[OFF_AKV + (sel * L_ + l) * P_ + p] + b;
}

// K11: feature logits + row softmax. grid 32 (per l), block 512 (8 waves x 4 g each).
__global__ void k_logits(float* __restrict__ out_fa, float* __restrict__ ws) {
    __shared__ __align__(16) float sq[512];
    __shared__ float lg[32];
    int l = blockIdx.x, tid = threadIdx.x, wv = tid >> 6, lane = tid & 63;
    sq[tid] = ws[OFF_QUERY + l * P_ + tid];
    __syncthreads();
    const float4* sq4 = (const float4*)sq;
    float4 q0 = sq4[lane * 2], q1 = sq4[lane * 2 + 1];
    for (int g = wv * 4; g < wv * 4 + 4; ++g) {
        const float4* kr = (const float4*)(ws + OFF_WKEY + g * P_);
        float4 a = kr[lane * 2], b = kr[lane * 2 + 1];
        float s = a.x * q0.x + a.y * q0.y + a.z * q0.z + a.w * q0.w
                + b.x * q1.x + b.y * q1.y + b.z * q1.z + b.w * q1.w;
        s = wred(s);
        if (lane == 0) lg[g] = s * SCALE;
    }
    __syncthreads();
    if (tid < 32) {
        float mx = -1e30f;
        for (int i = 0; i < 32; ++i) mx = fmaxf(mx, lg[i]);
        float S = 0.f;
        for (int i = 0; i < 32; ++i) S += expf(lg[i] - mx);
        float f = expf(lg[tid] - mx) / S;
        ws[OFF_FA + l * 32 + tid] = f;
        out_fa[l * 32 + tid] = f;
    }
}

// K12: EP[l,p] = sum_j FA[l,j]*WVAL[j,p]
__global__ void k_ep(float* __restrict__ ws) {
    __shared__ float fa[32];
    int l = blockIdx.x, p = threadIdx.x;
    if (p < 32) fa[p] = ws[OFF_FA + l * 32 + p];
    __syncthreads();
    float acc = 0.f;
    #pragma unroll 8
    for (int j = 0; j < L_; ++j) acc = fmaf(fa[j], ws[OFF_WVAL + j * P_ + p], acc);
    ws[OFF_EP + l * P_ + p] = acc;
}

// K13: split-K EP @ Wo -> AEVO. grid(32l, 4kc), block 512.
__global__ void k_evo_g(const float* __restrict__ Wo, float* __restrict__ ws) {
    __shared__ float sx[128];
    int d = threadIdx.x, l = blockIdx.x, kc = blockIdx.y;
    if (d < 128) sx[d] = ws[OFF_EP + l * P_ + kc * 128 + d];
    __syncthreads();
    float acc = 0.f;
    #pragma unroll 8
    for (int j = 0; j < 128; ++j) acc = fmaf(sx[j], Wo[(kc * 128 + j) * D_ + d], acc);
    atomicAdd(&ws[OFF_AEVO + l * D_ + d], acc);
}

// K14: EVOLVED = LN(WBASE + AEVO + bo)*g_in + b_in
__global__ void k_xin_ln(const float* __restrict__ bo, const float* __restrict__ g_in,
                         const float* __restrict__ b_in, float* __restrict__ ws) {
    __shared__ float buf[8];
    int l = blockIdx.x, d = threadIdx.x;
    float x = ws[OFF_WBASE + l * D_ + d] + ws[OFF_AEVO + l * D_ + d] + bo[d];
    float mean = fsum<512>(x, buf, d) * (1.0f / D_);
    float dx = x - mean;
    float var = fsum<512>(dx * dx, buf, d) * (1.0f / D_);
    ws[OFF_EVOLVED + l * D_ + d] = dx * rsqrtf(var + EPS_) * g_in[d] + b_in[d];
}

// K15: split-K EVOLVED @ Wa1 -> AH1 (pre-bias pre-relu). grid(32l,4hc,4kc), block 512.
__global__ void k_mlp1_g(const float* __restrict__ Wa1, float* __restrict__ ws) {
    __shared__ float sx[128];
    int tid = threadIdx.x, l = blockIdx.x, hc = blockIdx.y, kc = blockIdx.z;
    if (tid < 128) sx[tid] = ws[OFF_EVOLVED + l * D_ + kc * 128 + tid];
    __syncthreads();
    int h = hc * 512 + tid;
    float acc = 0.f;
    #pragma unroll 8
    for (int j = 0; j < 128; ++j) acc = fmaf(sx[j], Wa1[(kc * 128 + j) * H_ + h], acc);
    atomicAdd(&ws[OFF_AH1 + l * H_ + h], acc);
}

// K16: split-K relu(AH1+ba1) @ Wa2 -> AOUT. grid(32l, 16kc), block 512.
__global__ void k_mlp2_g(const float* __restrict__ Wa2, const float* __restrict__ ba1,
                         float* __restrict__ ws) {
    __shared__ float sh[128];
    int d = threadIdx.x, l = blockIdx.x, kc = blockIdx.y;
    if (d < 128) {
        int h = kc * 128 + d;
        sh[d] = fmaxf(ws[OFF_AH1 + l * H_ + h] + ba1[h], 0.f);
    }
    __syncthreads();
    float acc = 0.f;
    #pragma unroll 8
    for (int j = 0; j < 128; ++j) acc = fmaf(sh[j], Wa2[(kc * 128 + j) * D_ + d], acc);
    atomicAdd(&ws[OFF_AOUT + l * D_ + d], acc);
}

// K17: aligned = LN(EVOLVED + AOUT + ba2)*g_out + b_out -> fp32 out
__global__ void k_lnout(const float* __restrict__ ba2, const float* __restrict__ g_out,
                        const float* __restrict__ b_out, float* __restrict__ out_al,
                        float* __restrict__ ws) {
    __shared__ float buf[8];
    int l = blockIdx.x, d = threadIdx.x;
    float x = ws[OFF_EVOLVED + l * D_ + d] + ws[OFF_AOUT + l * D_ + d] + ba2[d];
    float mean = fsum<512>(x, buf, d) * (1.0f / D_);
    float dx = x - mean;
    float var = fsum<512>(dx * dx, buf, d) * (1.0f / D_);
    out_al[l * D_ + d] = dx * rsqrtf(var + EPS_) * g_out[d] + b_out[d];
}

// K18: aligned_prompts = broadcast(aligned), 64 MB float4 write. Runs LAST.
__global__ void k_bcast(float* __restrict__ out) {
    const float4* src = (const float4*)out;       // 4096 float4
    float4* dst = (float4*)(out + OFFO_AP);
    int idx = blockIdx.x * 256 + threadIdx.x;
    #pragma unroll
    for (int k = 0; k < 4; ++k) {
        int v = idx + k * 1048576;
        dst[v] = src[v & 4095];
    }
}

extern "C" void kernel_launch(void* const* d_in, const int* in_sizes, int n_in,
                              void* d_out, int out_size, void* d_ws, size_t ws_size,
                              hipStream_t stream) {
    const float* base = (const float*)d_in[0];
    const float* np   = (const float*)d_in[1];
    const float* te   = (const float*)d_in[2];
    const float* Wt   = (const float*)d_in[3];
    const float* bt   = (const float*)d_in[4];
    const float* Wq   = (const float*)d_in[5];
    const float* bq   = (const float*)d_in[6];
    const float* Wk   = (const float*)d_in[7];
    const float* bk   = (const float*)d_in[8];
    const float* Wv   = (const float*)d_in[9];
    const float* bv   = (const float*)d_in[10];
    const float* Wo   = (const float*)d_in[11];
    const float* bo   = (const float*)d_in[12];
    const float* Wa1  = (const float*)d_in[13];
    const float* ba1  = (const float*)d_in[14];
    const float* Wa2  = (const float*)d_in[15];
    const float* ba2  = (const float*)d_in[16];
    const float* g_in = (const float*)d_in[17];
    const float* b_in = (const float*)d_in[18];
    const float* g_out= (const float*)d_in[19];
    const float* b_out= (const float*)d_in[20];
    float* out = (float*)d_out;
    float* ws = out + OFFO_AP;   // scratch inside fp32 AP output region

    hipLaunchKernelGGL(k_zero,     dim3(145),        dim3(256), 0, stream, ws);
    hipLaunchKernelGGL(k_query_g,  dim3(33, 4),      dim3(512), 0, stream, np, te, Wq, Wt, ws);
    hipLaunchKernelGGL(k_query_ep, dim3(33),         dim3(512), 0, stream, bq, bt, ws);
    hipLaunchKernelGGL(k_pq,       dim3(1),          dim3(512), 0, stream, ws);
    hipLaunchKernelGGL(k_wk2,      dim3(64),         dim3(512), 0, stream, Wk, ws);
    hipLaunchKernelGGL(k_bbar,     dim3(1024),       dim3(512), 0, stream, base, ws);
    hipLaunchKernelGGL(k_soft,     dim3(1),          dim3(256), 0, stream, bk, out + OFFO_TW, ws);
    hipLaunchKernelGGL(k_wpart,    dim3(32, 32),     dim3(128), 0, stream, base, ws);
    hipLaunchKernelGGL(k_wred,     dim3(32),         dim3(512), 0, stream, ws);
    hipLaunchKernelGGL(k_wkv_g,    dim3(32, 2, 4),   dim3(512), 0, stream, Wk, Wv, ws);
    hipLaunchKernelGGL(k_wkv_ep,   dim3(32, 2),      dim3(512), 0, stream, bk, bv, ws);
    hipLaunchKernelGGL(k_logits,   dim3(32),         dim3(512), 0, stream, out + OFFO_FA, ws);
    hipLaunchKernelGGL(k_ep,       dim3(32),         dim3(512), 0, stream, ws);
    hipLaunchKernelGGL(k_evo_g,    dim3(32, 4),      dim3(512), 0, stream, Wo, ws);
    hipLaunchKernelGGL(k_xin_ln,   dim3(32),         dim3(512), 0, stream, bo, g_in, b_in, ws);
    hipLaunchKernelGGL(k_mlp1_g,   dim3(32, 4, 4),   dim3(512), 0, stream, Wa1, ws);
    hipLaunchKernelGGL(k_mlp2_g,   dim3(32, 16),     dim3(512), 0, stream, Wa2, ba1, ws);
    hipLaunchKernelGGL(k_lnout,    dim3(32),         dim3(512), 0, stream, ba2, g_out, b_out, out + OFFO_AL, ws);
    hipLaunchKernelGGL(k_bcast,    dim3(4096),       dim3(256), 0, stream, out);
}